// Round 1
// baseline (971.445 us; speedup 1.0000x reference)
//
#include <hip/hip_runtime.h>

#define SEQ 1024
#define BN  512
#define NT  64

__global__ void zero_out_kernel(float* o) { o[0] = 0.0f; }

extern "C" __global__ __launch_bounds__(64)
void crf_kernel(const float* __restrict__ emis,
                const int*   __restrict__ tags,
                const int*   __restrict__ mask,
                const float* __restrict__ startT,
                const float* __restrict__ endT,
                const float* __restrict__ trans,
                float* __restrict__ out)
{
    const int b    = blockIdx.x;
    const int lane = threadIdx.x;

    __shared__ __align__(16) float su[NT];

    // E columns in registers: Ecol[i] = exp(trans[i][lane])  (transitions are
    // constant over t and batch, so exp(T) is hoisted out of the scan entirely)
    float Ecol[NT];
    #pragma unroll
    for (int i = 0; i < NT; ++i)
        Ecol[i] = __expf(trans[i * NT + lane]);

    // ---- t = 0 init ----
    float em_c   = emis[(0 * BN + b) * NT + lane];
    int   tg_p   = tags[0 * BN + b];
    float alpha0 = startT[lane] + em_c;
    // wave-uniform offset M = alpha0[lane 0]; u_j = exp(alpha_j - M)
    float M = __int_as_float(__builtin_amdgcn_readfirstlane(__float_as_int(alpha0)));
    float u = __expf(alpha0 - M);

    float score = (lane == tg_p) ? alpha0 : 0.0f;   // start[tg0] + em0[tg0]
    int   lt    = tg_p;

    su[lane] = u;
    __syncthreads();

    // prefetch t = 1
    float em_n = emis[(1 * BN + b) * NT + lane];
    int   tg_n = tags[1 * BN + b];
    int   mk_n = mask[1 * BN + b];

    for (int t = 1; t < SEQ; ++t) {
        const float em_t = em_n;
        const int   tg_t = tg_n;
        const int   mk_t = mk_n;

        // prefetch t+1 (clamped)
        const int tn = (t + 1 < SEQ) ? (t + 1) : (SEQ - 1);
        em_n = emis[(tn * BN + b) * NT + lane];
        tg_n = tags[tn * BN + b];
        mk_n = mask[tn * BN + b];

        // numerator transition row (L1-cached, uniform row; off critical chain)
        float Trow = trans[tg_p * NT + lane];
        // w_j = exp(em_t[j])  (off critical chain; em prefetched)
        float w = __expf(em_t);

        // s_j = sum_i u_i * E[i][j]  via LDS broadcast reads
        float4 acc = make_float4(0.f, 0.f, 0.f, 0.f);
        const float4* su4 = (const float4*)su;
        #pragma unroll
        for (int k = 0; k < NT / 4; ++k) {
            float4 v = su4[k];
            acc.x += v.x * Ecol[4 * k + 0];
            acc.y += v.y * Ecol[4 * k + 1];
            acc.z += v.z * Ecol[4 * k + 2];
            acc.w += v.w * Ecol[4 * k + 3];
        }
        float s   = (acc.x + acc.y) + (acc.z + acc.w);
        float swv = s * w;
        // renormalize so that u_0 = 1: C = swv[lane 0]
        float C = __int_as_float(__builtin_amdgcn_readfirstlane(__float_as_int(swv)));

        if (mk_t) {                               // wave-uniform branch
            u = swv * __builtin_amdgcn_rcpf(C);
            M += __logf(C);                       // log C = log s_0 + em_0
            if (lane == tg_t) score += em_t + Trow;
            lt = tg_t;
        }

        __syncthreads();          // prev reads done before overwrite (WAR)
        su[lane] = u;
        __syncthreads();          // write visible before next step's reads

        tg_p = tg_t;
    }

    // ---- epilogue ----
    if (lane == lt) score += endT[lane];
    float v  = u * __expf(endT[lane]);  // exp(alpha - M + end)
    float sp = score;
    #pragma unroll
    for (int off = 32; off > 0; off >>= 1) {
        v  += __shfl_xor(v,  off, 64);
        sp += __shfl_xor(sp, off, 64);
    }
    if (lane == 0) {
        float denom = M + __logf(v);
        atomicAdd(out, sp - denom);
    }
}

extern "C" void kernel_launch(void* const* d_in, const int* in_sizes, int n_in,
                              void* d_out, int out_size, void* d_ws, size_t ws_size,
                              hipStream_t stream)
{
    const float* emis   = (const float*)d_in[0];
    const int*   tags   = (const int*)  d_in[1];
    const int*   mask   = (const int*)  d_in[2];
    const float* startT = (const float*)d_in[3];
    const float* endT   = (const float*)d_in[4];
    const float* trans  = (const float*)d_in[5];
    float* out = (float*)d_out;

    zero_out_kernel<<<1, 1, 0, stream>>>(out);
    crf_kernel<<<dim3(BN), dim3(NT), 0, stream>>>(emis, tags, mask,
                                                  startT, endT, trans, out);
}

// Round 2
// 958.820 us; speedup vs baseline: 1.0132x; 1.0132x over previous
//
#include <hip/hip_runtime.h>

#define SEQ 1024
#define BN  512
#define NT  64

typedef float vf16 __attribute__((ext_vector_type(16)));

__global__ void zero_out_kernel(float* o) { o[0] = 0.0f; }

// E element i (i constant after unroll -> folds to a single VGPR ref)
#define EAT(i) ((i) < 16 ? E0[(i) & 15] : (i) < 32 ? E1[(i) & 15] : \
                (i) < 48 ? E2[(i) & 15] : E3[(i) & 15])

extern "C" __global__ __launch_bounds__(64, 1)
void crf_kernel(const float* __restrict__ emis,
                const int*   __restrict__ tags,
                const int*   __restrict__ mask,
                const float* __restrict__ startT,
                const float* __restrict__ endT,
                const float* __restrict__ trans,
                float* __restrict__ out)
{
    const int b    = blockIdx.x;
    const int lane = threadIdx.x;

    // Single-wave block: no __syncthreads anywhere. DS pipe is in-order per
    // wave, and the su write data-depends on the su reads, so cross-lane
    // visibility through LDS is guaranteed by HW ordering.
    __shared__ __align__(16) float su[NT];

    // E[i] = exp(trans[i][lane]) held in VGPRs (4 x vec16 = 64 regs).
    // launch_bounds(64,1) lifts the VGPR cap so these do NOT spill.
    vf16 E0, E1, E2, E3;
    #pragma unroll
    for (int i = 0; i < 16; ++i) E0[i] = __expf(trans[(i     ) * NT + lane]);
    #pragma unroll
    for (int i = 0; i < 16; ++i) E1[i] = __expf(trans[(i + 16) * NT + lane]);
    #pragma unroll
    for (int i = 0; i < 16; ++i) E2[i] = __expf(trans[(i + 32) * NT + lane]);
    #pragma unroll
    for (int i = 0; i < 16; ++i) E3[i] = __expf(trans[(i + 48) * NT + lane]);

    // ---- t = 0 init ----
    float em0    = emis[(0 * BN + b) * NT + lane];
    int   tg_p   = tags[0 * BN + b];
    float alpha0 = startT[lane] + em0;
    float M = __int_as_float(__builtin_amdgcn_readfirstlane(__float_as_int(alpha0)));
    float u = __expf(alpha0 - M);           // u_0 == 1

    float score = (lane == tg_p) ? alpha0 : 0.0f;
    int   lt    = tg_p;
    int   esum  = 0;                        // exact integer exponent offset

    su[lane] = u;

    // ---- depth-4 prefetch pipeline (em / tag / mask for t .. t+3) ----
    float emA = emis[(1 * BN + b) * NT + lane];
    float emB = emis[(2 * BN + b) * NT + lane];
    float emC = emis[(3 * BN + b) * NT + lane];
    float emD = emis[(4 * BN + b) * NT + lane];
    int tgA = tags[1 * BN + b], tgB = tags[2 * BN + b];
    int tgC = tags[3 * BN + b], tgD = tags[4 * BN + b];
    int mkA = mask[1 * BN + b], mkB = mask[2 * BN + b];
    int mkC = mask[3 * BN + b], mkD = mask[4 * BN + b];

    // numerator transition row, 1 step ahead (L1-resident 16KB table)
    float Trow_n = trans[tg_p * NT + lane];

    for (int t = 1; t < SEQ; ++t) {
        const float em_t = emA;
        const int   tg_t = tgA;
        const int   mk_t = mkA;
        const float Trow = Trow_n;

        // rotate pipeline, issue loads for t+4 (clamped)
        emA = emB; emB = emC; emC = emD;
        tgA = tgB; tgB = tgC; tgC = tgD;
        mkA = mkB; mkB = mkC; mkC = mkD;
        int tn = t + 4; if (tn > SEQ - 1) tn = SEQ - 1;
        emD = emis[(tn * BN + b) * NT + lane];
        tgD = tags[tn * BN + b];
        mkD = mask[tn * BN + b];

        float w = __expf(em_t);             // off the u-chain (em prefetched)

        // s_j = sum_i u_i * E[i][j]; LDS broadcast reads, 8 FMA chains
        const float4* su4 = (const float4*)su;
        float4 aA = make_float4(0.f, 0.f, 0.f, 0.f);
        float4 aB = make_float4(0.f, 0.f, 0.f, 0.f);
        #pragma unroll
        for (int k = 0; k < 8; ++k) {
            float4 v0 = su4[2 * k];
            float4 v1 = su4[2 * k + 1];
            aA.x = fmaf(v0.x, EAT(8 * k + 0), aA.x);
            aA.y = fmaf(v0.y, EAT(8 * k + 1), aA.y);
            aA.z = fmaf(v0.z, EAT(8 * k + 2), aA.z);
            aA.w = fmaf(v0.w, EAT(8 * k + 3), aA.w);
            aB.x = fmaf(v1.x, EAT(8 * k + 4), aB.x);
            aB.y = fmaf(v1.y, EAT(8 * k + 5), aB.y);
            aB.z = fmaf(v1.z, EAT(8 * k + 6), aB.z);
            aB.w = fmaf(v1.w, EAT(8 * k + 7), aB.w);
        }
        float s   = ((aA.x + aA.y) + (aA.z + aA.w))
                  + ((aB.x + aB.y) + (aB.z + aB.w));
        float swv = s * w;

        // exponent-only renorm: shift so lane-0's value has mantissa in [1,2).
        // Exact integer accumulation replaces per-step logf.
        int ex = (__float_as_int(swv) >> 23) & 255;
        int e  = __builtin_amdgcn_readfirstlane(ex);
        float un = ldexpf(swv, 127 - e);

        if (mk_t) {                          // wave-uniform branch
            u = un;
            esum += e - 127;
            if (lane == tg_t) score += em_t + Trow;
            lt = tg_t;
        }

        su[lane] = u;                        // in-order DS: next step's reads see it
        tg_p   = tg_t;
        Trow_n = trans[tg_p * NT + lane];
    }

    // ---- epilogue ----
    if (lane == lt) score += endT[lane];
    float v  = u * __expf(endT[lane]);       // exp(alpha - M - esum*ln2 + end)
    float sp = score;
    #pragma unroll
    for (int off = 32; off > 0; off >>= 1) {
        v  += __shfl_xor(v,  off, 64);
        sp += __shfl_xor(sp, off, 64);
    }
    if (lane == 0) {
        float denom = M + (float)esum * 0.69314718055994531f + __logf(v);
        atomicAdd(out, sp - denom);
    }
}

extern "C" void kernel_launch(void* const* d_in, const int* in_sizes, int n_in,
                              void* d_out, int out_size, void* d_ws, size_t ws_size,
                              hipStream_t stream)
{
    const float* emis   = (const float*)d_in[0];
    const int*   tags   = (const int*)  d_in[1];
    const int*   mask   = (const int*)  d_in[2];
    const float* startT = (const float*)d_in[3];
    const float* endT   = (const float*)d_in[4];
    const float* trans  = (const float*)d_in[5];
    float* out = (float*)d_out;

    zero_out_kernel<<<1, 1, 0, stream>>>(out);
    crf_kernel<<<dim3(BN), dim3(NT), 0, stream>>>(emis, tags, mask,
                                                  startT, endT, trans, out);
}

// Round 3
// 551.131 us; speedup vs baseline: 1.7626x; 1.7397x over previous
//
#include <hip/hip_runtime.h>

#define SEQ 1024
#define BN  512
#define NT  64

__global__ void zero_out_kernel(float* o) { o[0] = 0.0f; }

extern "C" __global__ __launch_bounds__(64, 1)
void crf_kernel(const float* __restrict__ emis,
                const int*   __restrict__ tags,
                const int*   __restrict__ mask,
                const float* __restrict__ startT,
                const float* __restrict__ endT,
                const float* __restrict__ trans,
                float* __restrict__ out)
{
    const int b    = blockIdx.x;
    const int lane = threadIdx.x;

    // All per-step state lives in LDS so the K-loop issues ZERO vmem except
    // the emissions prefetch stream (keeps vmcnt waits off the chain).
    __shared__ __align__(16) float4 E4[16 * NT];   // E4[i4*64+j] = {exp(T[4i4+r][j])}
    __shared__ __align__(16) float  su[NT];        // u vector (broadcast reads)
    __shared__ __align__(16) float  strans[NT * NT];
    __shared__ int stag[SEQ];
    __shared__ int smk[SEQ];

    // ---- one-time staging (single wave, in-order DS, no barriers) ----
    // trans -> LDS (coalesced float4)
    {
        const float4* t4 = (const float4*)trans;
        float4* s4 = (float4*)strans;
        #pragma unroll
        for (int k = 0; k < (NT * NT / 4) / NT; ++k)       // 16 iters
            s4[k * NT + lane] = t4[k * NT + lane];
    }
    // E4 fragment layout: lane j stores {exp(T[4i4+r][j])} as one float4
    #pragma unroll
    for (int i4 = 0; i4 < 16; ++i4) {
        float4 e;
        e.x = __expf(trans[(4 * i4 + 0) * NT + lane]);
        e.y = __expf(trans[(4 * i4 + 1) * NT + lane]);
        e.z = __expf(trans[(4 * i4 + 2) * NT + lane]);
        e.w = __expf(trans[(4 * i4 + 3) * NT + lane]);
        E4[(i4 << 6) + lane] = e;
    }
    // tags/mask columns for this batch -> LDS (one-time uncoalesced gather)
    #pragma unroll
    for (int c = 0; c < SEQ / NT; ++c) {
        int t = c * NT + lane;
        stag[t] = tags[t * BN + b];
        smk[t]  = mask[t * BN + b];
    }
    __threadfence_block();   // one-time; orders staging writes before loop reads

    // ---- t = 0 init ----
    float em0    = emis[(0 * BN + b) * NT + lane];
    int   tg_p   = stag[0];
    float alpha0 = startT[lane] + em0;
    float M = __int_as_float(__builtin_amdgcn_readfirstlane(__float_as_int(alpha0)));
    float u = __expf(alpha0 - M);            // u_0 == 1
    float score = (lane == tg_p) ? alpha0 : 0.0f;
    int   lt    = tg_p;
    int   esum  = 0;
    su[lane] = u;

    // ---- depth-4 emissions prefetch (the ONLY vmem in the loop) ----
    float emA = emis[(1 * BN + b) * NT + lane];
    float emB = emis[(2 * BN + b) * NT + lane];
    float emC = emis[(3 * BN + b) * NT + lane];
    float emD = emis[(4 * BN + b) * NT + lane];

    #pragma unroll 2
    for (int t = 1; t < SEQ; ++t) {
        const float em_t = emA;
        emA = emB; emB = emC; emC = emD;
        int tn = t + 4; if (tn > SEQ - 1) tn = SEQ - 1;
        emD = emis[(tn * BN + b) * NT + lane];

        const int   tg_t = stag[t];                  // LDS broadcast
        const int   mk_t = smk[t];
        const float Trow = strans[tg_p * NT + lane]; // conflict-free b32

        float w = __expf(em_t);                      // off the u-chain

        // s_j = sum_i u_i * E[i][j] : su broadcasts + E fragments, 8 FMA chains
        const float4* su4 = (const float4*)su;
        float4 aA = make_float4(0.f, 0.f, 0.f, 0.f);
        float4 aB = make_float4(0.f, 0.f, 0.f, 0.f);
        #pragma unroll
        for (int i4 = 0; i4 < 16; i4 += 2) {
            float4 v0 = su4[i4];
            float4 v1 = su4[i4 + 1];
            float4 e0 = E4[(i4 << 6) + lane];
            float4 e1 = E4[((i4 + 1) << 6) + lane];
            aA.x = fmaf(v0.x, e0.x, aA.x);
            aA.y = fmaf(v0.y, e0.y, aA.y);
            aA.z = fmaf(v0.z, e0.z, aA.z);
            aA.w = fmaf(v0.w, e0.w, aA.w);
            aB.x = fmaf(v1.x, e1.x, aB.x);
            aB.y = fmaf(v1.y, e1.y, aB.y);
            aB.z = fmaf(v1.z, e1.z, aB.z);
            aB.w = fmaf(v1.w, e1.w, aB.w);
        }
        float s   = ((aA.x + aA.y) + (aA.z + aA.w))
                  + ((aB.x + aB.y) + (aB.z + aB.w));
        float swv = s * w;

        // exponent-only renorm (no per-step log): shift by lane-0's exponent
        int ex = (__float_as_int(swv) >> 23) & 255;
        int e  = __builtin_amdgcn_readfirstlane(ex);
        float un = ldexpf(swv, 127 - e);

        if (mk_t) {                                   // wave-uniform
            u = un;
            esum += e - 127;
            if (lane == tg_t) score += em_t + Trow;
            lt = tg_t;
        }
        su[lane] = u;                                 // in-order DS
        tg_p = tg_t;                                  // advances regardless of mask
    }

    // ---- epilogue ----
    if (lane == lt) score += endT[lane];
    float v  = u * __expf(endT[lane]);
    float sp = score;
    #pragma unroll
    for (int off = 32; off > 0; off >>= 1) {
        v  += __shfl_xor(v,  off, 64);
        sp += __shfl_xor(sp, off, 64);
    }
    if (lane == 0) {
        float denom = M + (float)esum * 0.69314718055994531f + __logf(v);
        atomicAdd(out, sp - denom);
    }
}

extern "C" void kernel_launch(void* const* d_in, const int* in_sizes, int n_in,
                              void* d_out, int out_size, void* d_ws, size_t ws_size,
                              hipStream_t stream)
{
    const float* emis   = (const float*)d_in[0];
    const int*   tags   = (const int*)  d_in[1];
    const int*   mask   = (const int*)  d_in[2];
    const float* startT = (const float*)d_in[3];
    const float* endT   = (const float*)d_in[4];
    const float* trans  = (const float*)d_in[5];
    float* out = (float*)d_out;

    zero_out_kernel<<<1, 1, 0, stream>>>(out);
    crf_kernel<<<dim3(BN), dim3(NT), 0, stream>>>(emis, tags, mask,
                                                  startT, endT, trans, out);
}